// Round 17
// baseline (59.272 us; speedup 1.0000x reference)
//
#include <hip/hip_runtime.h>
#include <hip/hip_bf16.h>

// SGCN fused: y = conv1x1(x, W)+b ; out[n,c,t,w] = sum_{k,v} y[n,k,c,t,v]*A[k,v,w]
// x:[64,64,300,25] f32, A:[3,25,25] f32, W:[64,192] f32, b:[192] f32
// d_out = [out (64*64*300*25) ; A (1875)] f32
//
// Round 17: 2-chunk software pipeline (T14). r10..r16 pinned at profiled
// 87-89us with ~10 waves/CU across 4 structural variants -> resident blocks
// are phase-locked; staging HBM wait is exposed. Fix: each block overlaps
// chunk1's loads with chunk0's compute (issue-early / write-late into the
// idle LDS buffer). Grid 25x64=1600 (6.25 blocks/CU, stays fed - r11's 640
// under-filled). LDS dbuf 49KB (3 blocks/CU), (256,2) (r11: VGPR128 no spill).
// Staging/swizzle/compute = r14 verbatim (bit-exact): float4 staging,
// t-mixed swizzle f(row)=(row&7)^(row>>5), permuted-row xs so stage1 D-frag
// == stage2 A-frag (zero shuffle), bias via MFMA C-init.

#define TT 6
#define NCHUNK 2
#define GRIDX 25                 // 300 / (TT*NCHUNK)
#define NB 64
#define CI 64
#define TDIM 300
#define VDIM 25
#define CO 64
#define KK 3

#define XROWS (TT*32)            // 192 rows, [192][128B], swz ((row&7)^(row>>5))<<4
#define SMEM_BYTES (XROWS*128)   // 24576 B per buffer

#define WBUF_BYTES (KK*4*2*64*16)   // 24576: [k][wave][half][lane] 16B frags
#define ABUF_BYTES (KK*2*64*16)     //  6144: [k][nt][lane] 16B frags

typedef __attribute__((ext_vector_type(8))) short bf16x8;
typedef __attribute__((ext_vector_type(4))) float f32x4;
typedef __attribute__((ext_vector_type(4))) int i32x4;
typedef __attribute__((ext_vector_type(4), aligned(4))) float f32x4u;  // 4B-aligned vec load

__device__ __forceinline__ unsigned int pack2(float lo, float hi) {
    __hip_bfloat162 h = __float22bfloat162_rn(make_float2(lo, hi));  // v_cvt_pk_bf16_f32
    unsigned int u;
    __builtin_memcpy(&u, &h, 4);
    return u;
}
__device__ __forceinline__ unsigned short f2bf(float f) {
    __hip_bfloat16 h = __float2bfloat16(f);
    unsigned short u;
    __builtin_memcpy(&u, &h, 2);
    return u;
}

// ---- prep: bf16 B-fragments for W and A in ws; copy A to out tail ----
__global__ void sgcn_prep(const float* __restrict__ A, const float* __restrict__ W,
                          unsigned int* __restrict__ wbuf, unsigned int* __restrict__ abuf,
                          float* __restrict__ outA) {
    int id = blockIdx.x * 256 + threadIdx.x;    // grid 8*256
    if (id < KK * 4 * 2 * 64) {                 // 1536 W-fragments
        int l  = id & 63;
        int h  = (id >> 6) & 1;
        int wq = (id >> 7) & 3;
        int k  = id >> 9;
        int c  = wq * 16 + (l & 15);
        int ib = (l >> 4) * 8 + h * 32;
        unsigned int pk[4];
        #pragma unroll
        for (int j = 0; j < 4; ++j)
            pk[j] = pack2(W[(size_t)(ib + 2*j)     * (KK*CO) + k*CO + c],
                          W[(size_t)(ib + 2*j + 1) * (KK*CO) + k*CO + c]);
        *(uint4*)(wbuf + id * 4) = make_uint4(pk[0], pk[1], pk[2], pk[3]);
    }
    if (id < KK * 2 * 64) {                     // 384 A-fragments, v zero-padded to 32
        int l  = id & 63;
        int nt = (id >> 6) & 1;
        int k  = id >> 7;
        int w  = nt * 16 + (l & 15);
        int vb = (l >> 4) * 8;
        unsigned int pk[4];
        #pragma unroll
        for (int j = 0; j < 4; ++j) {
            int v0 = vb + 2*j, v1 = v0 + 1;
            unsigned short u0 = (v0 < VDIM && w < VDIM) ? f2bf(A[k*VDIM*VDIM + v0*VDIM + w]) : (unsigned short)0;
            unsigned short u1 = (v1 < VDIM && w < VDIM) ? f2bf(A[k*VDIM*VDIM + v1*VDIM + w]) : (unsigned short)0;
            pk[j] = (unsigned int)u0 | ((unsigned int)u1 << 16);
        }
        *(uint4*)(abuf + id * 4) = make_uint4(pk[0], pk[1], pk[2], pk[3]);
    }
    if (id < KK * VDIM * VDIM) outA[id] = A[id];   // tuple output 1 (exact)
}

__global__ __launch_bounds__(256, 2) void sgcn_fused(
    const float* __restrict__ x, const float* __restrict__ b,
    const unsigned int* __restrict__ wbuf, const unsigned int* __restrict__ abuf,
    float* __restrict__ out)
{
    __shared__ __align__(16) char smem[2][SMEM_BYTES];
    const int tid  = threadIdx.x;
    const int lane = tid & 63;
    const int wid  = tid >> 6;
    const int n    = blockIdx.y;
    const int t0   = blockIdx.x * (TT * NCHUNK);
    const int l15  = lane & 15;
    const int g    = lane >> 4;
    const int i0   = g * 8;              // K-chunk base within 32
    const int c    = wid * 16 + l15;

    // Staging task decode: id = tid + j*256, j=0..5 over 1536 tasks.
    // id -> i2 = id/48, rem = id%48, t = rem>>3, grp = rem&7; v0 = 4*grp;
    // rows rr = 16*(grp&1) + 4*(grp>>1) + p (permuted order).
    float q0[6][4], q1[6][4];

    #define STAGE_LOAD(TBASE)                                                        \
        _Pragma("unroll")                                                            \
        for (int j = 0; j < 6; ++j) {                                                \
            int id  = tid + j * 256;                                                 \
            int i2  = id / 48;                                                       \
            int rem = id - i2 * 48;                                                  \
            int t   = rem >> 3;                                                      \
            int grp = rem & 7;                                                       \
            const float* pc0 = x + (((size_t)n * CI + 2*i2) * TDIM + ((TBASE) + t)) * VDIM + 4*grp; \
            const float* pc1 = pc0 + TDIM * VDIM;                                    \
            f32x4 a0 = {0.f, 0.f, 0.f, 0.f};                                         \
            f32x4 a1 = {0.f, 0.f, 0.f, 0.f};                                         \
            if (grp < 6)      { a0 = *(const f32x4u*)pc0; a1 = *(const f32x4u*)pc1; }\
            else if (grp == 6){ a0.x = pc0[0];            a1.x = pc1[0]; }           \
            q0[j][0]=a0.x; q0[j][1]=a0.y; q0[j][2]=a0.z; q0[j][3]=a0.w;              \
            q1[j][0]=a1.x; q1[j][1]=a1.y; q1[j][2]=a1.z; q1[j][3]=a1.w;              \
        }

    #define STAGE_WRITE(BUF)                                                         \
        _Pragma("unroll")                                                            \
        for (int j = 0; j < 6; ++j) {                                                \
            int id  = tid + j * 256;                                                 \
            int i2  = id / 48;                                                       \
            int rem = id - i2 * 48;                                                  \
            int t   = rem >> 3;                                                      \
            int grp = rem & 7;                                                       \
            int rr0 = ((grp & 1) << 4) + ((grp >> 1) << 2);                          \
            int rbase = t * 32 + rr0;                                                \
            int m   = rr0 & 7;                                                       \
            _Pragma("unroll")                                                        \
            for (int p = 0; p < 4; ++p) {                                            \
                int fx = ((m + p) & 7) ^ t;                                          \
                int addr = (rbase + p) * 128 + ((4*i2) ^ (fx << 4));                 \
                *(unsigned int*)((BUF) + addr) = pack2(q0[j][p], q1[j][p]);          \
            }                                                                        \
        }

    // ---- prologue: stage chunk 0; frag loads overlap the HBM wait ----
    STAGE_LOAD(t0);

    bf16x8 WB[KK][2], AB[KK][2];
    float bv[KK];
    #pragma unroll
    for (int k = 0; k < KK; ++k) {
        WB[k][0] = *(const bf16x8*)(wbuf + (((k*4 + wid)*2 + 0)*64 + lane)*4);
        WB[k][1] = *(const bf16x8*)(wbuf + (((k*4 + wid)*2 + 1)*64 + lane)*4);
        AB[k][0] = *(const bf16x8*)(abuf + ((k*2 + 0)*64 + lane)*4);
        AB[k][1] = *(const bf16x8*)(abuf + ((k*2 + 1)*64 + lane)*4);
        bv[k]    = b[k*CO + c];
    }

    STAGE_WRITE(&smem[0][0]);
    __syncthreads();

    const size_t cs = (size_t)TDIM * VDIM;   // out stride for c+1

    #pragma unroll
    for (int ch = 0; ch < NCHUNK; ++ch) {
        const char* rbuf = &smem[ch][0];
        const int   tg0  = t0 + ch * TT;

        if (ch == 0) STAGE_LOAD(t0 + TT);    // chunk1 loads in flight under compute

        #pragma unroll
        for (int t = 0; t < TT; ++t) {
            // A-frags for this t (reused across all k); rows j&7 = l15&7, j>>5 = t
            int j0 = t*32 + l15;
            int j1 = j0 + 16;
            const char* p0 = rbuf + j0*128;
            const char* p1 = rbuf + j1*128;
            int fx = ((l15 & 7) ^ t) << 4;
            bf16x8 A00 = *(const bf16x8*)(p0 + ((2*i0)      ^ fx));
            bf16x8 A01 = *(const bf16x8*)(p0 + ((2*i0 + 64) ^ fx));
            bf16x8 A10 = *(const bf16x8*)(p1 + ((2*i0)      ^ fx));
            bf16x8 A11 = *(const bf16x8*)(p1 + ((2*i0 + 64) ^ fx));

            f32x4 accA = {0.f, 0.f, 0.f, 0.f};
            f32x4 accB = {0.f, 0.f, 0.f, 0.f};
            #pragma unroll
            for (int k = 0; k < KK; ++k) {
                f32x4 D0 = {bv[k], bv[k], bv[k], bv[k]};   // bias via C-operand
                f32x4 D1 = D0;
                D0 = __builtin_amdgcn_mfma_f32_16x16x32_bf16(A00, WB[k][0], D0, 0, 0, 0);
                D0 = __builtin_amdgcn_mfma_f32_16x16x32_bf16(A01, WB[k][1], D0, 0, 0, 0);
                D1 = __builtin_amdgcn_mfma_f32_16x16x32_bf16(A10, WB[k][0], D1, 0, 0, 0);
                D1 = __builtin_amdgcn_mfma_f32_16x16x32_bf16(A11, WB[k][1], D1, 0, 0, 0);
                // lane holds y[c][v]: D0 -> v=8g+{0..3}, D1 -> v=8g+4+{0..3}
                // == exactly the stage2 A-fragment (k-elements 8g..8g+7).
                i32x4 pav = {(int)pack2(D0.x, D0.y), (int)pack2(D0.z, D0.w),
                             (int)pack2(D1.x, D1.y), (int)pack2(D1.z, D1.w)};
                bf16x8 PA = __builtin_bit_cast(bf16x8, pav);
                accA = __builtin_amdgcn_mfma_f32_16x16x32_bf16(PA, AB[k][0], accA, 0, 0, 0);
                accB = __builtin_amdgcn_mfma_f32_16x16x32_bf16(PA, AB[k][1], accB, 0, 0, 0);
            }
            // ---- store this t: D2 col=w=l15(+16*nt), rows c = wid*16 + 4g + p ----
            size_t base = (((size_t)n * CO + (wid*16 + 4*g)) * TDIM + (tg0 + t)) * VDIM + l15;
            out[base]        = accA.x;
            out[base + cs]   = accA.y;
            out[base + 2*cs] = accA.z;
            out[base + 3*cs] = accA.w;
            if (l15 < VDIM - 16) {
                size_t base2 = base + 16;
                out[base2]        = accB.x;
                out[base2 + cs]   = accB.y;
                out[base2 + 2*cs] = accB.z;
                out[base2 + 3*cs] = accB.w;
            }
        }

        if (ch == 0) {
            STAGE_WRITE(&smem[1][0]);        // lands in the idle buffer
            __syncthreads();                 // chunk1 ready
        }
    }
    #undef STAGE_LOAD
    #undef STAGE_WRITE
}

extern "C" void kernel_launch(void* const* d_in, const int* in_sizes, int n_in,
                              void* d_out, int out_size, void* d_ws, size_t ws_size,
                              hipStream_t stream) {
    const float* x = (const float*)d_in[0];
    const float* A = (const float*)d_in[1];
    const float* W = (const float*)d_in[2];
    const float* b = (const float*)d_in[3];
    float* out = (float*)d_out;

    unsigned int* wbuf = (unsigned int*)d_ws;
    unsigned int* abuf = (unsigned int*)((char*)d_ws + WBUF_BYTES);

    const size_t out_elems = (size_t)NB * CO * TDIM * VDIM;
    sgcn_prep<<<8, 256, 0, stream>>>(A, W, wbuf, abuf, out + out_elems);

    dim3 grid(GRIDX, NB);
    sgcn_fused<<<grid, 256, 0, stream>>>(x, b, wbuf, abuf, out);
}

// Round 18
// 58.585 us; speedup vs baseline: 1.0117x; 1.0117x over previous
//
#include <hip/hip_runtime.h>
#include <hip/hip_bf16.h>

// SGCN fused: y = conv1x1(x, W)+b ; out[n,c,t,w] = sum_{k,v} y[n,k,c,t,v]*A[k,v,w]
// x:[64,64,300,25] f32, A:[3,25,25] f32, W:[64,192] f32, b:[192] f32
// d_out = [out (64*64*300*25) ; A (1875)] f32
//
// Round 18 = Round 17 pipeline with TT=5 (dbuf 40KB -> 4 blocks/CU).
// r17 showed the 2-chunk pipeline fully compensates ~1 block of lost
// residency (18% occ, same 87us) - but 49KB LDS spent the residency it
// needed. TT=5: 20KB/buffer, grid 30x64=1920 (7.5/CU), 4 resident -> the
// pipeline and residency stack. 1280 staging tasks = 5/thread (decode /40).
// Staging/swizzle/compute math identical semantics (bit-exact path):
// float4 staging, t-mixed swizzle f(row)=(row&7)^(row>>5), permuted-row xs
// so stage1 D-frag == stage2 A-frag (zero shuffle), bias via MFMA C-init.

#define TT 5
#define NCHUNK 2
#define GRIDX 30                 // 300 / (TT*NCHUNK)
#define NB 64
#define CI 64
#define TDIM 300
#define VDIM 25
#define CO 64
#define KK 3
#define NTASK 5                  // staging tasks per thread = 32*TT*8/256

#define XROWS (TT*32)            // 160 rows, [160][128B], swz ((row&7)^(row>>5))<<4
#define SMEM_BYTES (XROWS*128)   // 20480 B per buffer

#define WBUF_BYTES (KK*4*2*64*16)   // 24576: [k][wave][half][lane] 16B frags
#define ABUF_BYTES (KK*2*64*16)     //  6144: [k][nt][lane] 16B frags

typedef __attribute__((ext_vector_type(8))) short bf16x8;
typedef __attribute__((ext_vector_type(4))) float f32x4;
typedef __attribute__((ext_vector_type(4))) int i32x4;
typedef __attribute__((ext_vector_type(4), aligned(4))) float f32x4u;  // 4B-aligned vec load

__device__ __forceinline__ unsigned int pack2(float lo, float hi) {
    __hip_bfloat162 h = __float22bfloat162_rn(make_float2(lo, hi));  // v_cvt_pk_bf16_f32
    unsigned int u;
    __builtin_memcpy(&u, &h, 4);
    return u;
}
__device__ __forceinline__ unsigned short f2bf(float f) {
    __hip_bfloat16 h = __float2bfloat16(f);
    unsigned short u;
    __builtin_memcpy(&u, &h, 2);
    return u;
}

// ---- prep: bf16 B-fragments for W and A in ws; copy A to out tail ----
__global__ void sgcn_prep(const float* __restrict__ A, const float* __restrict__ W,
                          unsigned int* __restrict__ wbuf, unsigned int* __restrict__ abuf,
                          float* __restrict__ outA) {
    int id = blockIdx.x * 256 + threadIdx.x;    // grid 8*256
    if (id < KK * 4 * 2 * 64) {                 // 1536 W-fragments
        int l  = id & 63;
        int h  = (id >> 6) & 1;
        int wq = (id >> 7) & 3;
        int k  = id >> 9;
        int c  = wq * 16 + (l & 15);
        int ib = (l >> 4) * 8 + h * 32;
        unsigned int pk[4];
        #pragma unroll
        for (int j = 0; j < 4; ++j)
            pk[j] = pack2(W[(size_t)(ib + 2*j)     * (KK*CO) + k*CO + c],
                          W[(size_t)(ib + 2*j + 1) * (KK*CO) + k*CO + c]);
        *(uint4*)(wbuf + id * 4) = make_uint4(pk[0], pk[1], pk[2], pk[3]);
    }
    if (id < KK * 2 * 64) {                     // 384 A-fragments, v zero-padded to 32
        int l  = id & 63;
        int nt = (id >> 6) & 1;
        int k  = id >> 7;
        int w  = nt * 16 + (l & 15);
        int vb = (l >> 4) * 8;
        unsigned int pk[4];
        #pragma unroll
        for (int j = 0; j < 4; ++j) {
            int v0 = vb + 2*j, v1 = v0 + 1;
            unsigned short u0 = (v0 < VDIM && w < VDIM) ? f2bf(A[k*VDIM*VDIM + v0*VDIM + w]) : (unsigned short)0;
            unsigned short u1 = (v1 < VDIM && w < VDIM) ? f2bf(A[k*VDIM*VDIM + v1*VDIM + w]) : (unsigned short)0;
            pk[j] = (unsigned int)u0 | ((unsigned int)u1 << 16);
        }
        *(uint4*)(abuf + id * 4) = make_uint4(pk[0], pk[1], pk[2], pk[3]);
    }
    if (id < KK * VDIM * VDIM) outA[id] = A[id];   // tuple output 1 (exact)
}

__global__ __launch_bounds__(256, 2) void sgcn_fused(
    const float* __restrict__ x, const float* __restrict__ b,
    const unsigned int* __restrict__ wbuf, const unsigned int* __restrict__ abuf,
    float* __restrict__ out)
{
    __shared__ __align__(16) char smem[2][SMEM_BYTES];
    const int tid  = threadIdx.x;
    const int lane = tid & 63;
    const int wid  = tid >> 6;
    const int n    = blockIdx.y;
    const int t0   = blockIdx.x * (TT * NCHUNK);
    const int l15  = lane & 15;
    const int g    = lane >> 4;
    const int i0   = g * 8;              // K-chunk base within 32
    const int c    = wid * 16 + l15;

    // Staging task decode: id = tid + j*256, j=0..4 over 1280 tasks.
    // id -> i2 = id/40, rem = id%40, t = rem>>3, grp = rem&7; v0 = 4*grp;
    // rows rr = 16*(grp&1) + 4*(grp>>1) + p (permuted order).
    float q0[NTASK][4], q1[NTASK][4];

    #define STAGE_LOAD(TBASE)                                                        \
        _Pragma("unroll")                                                            \
        for (int j = 0; j < NTASK; ++j) {                                            \
            int id  = tid + j * 256;                                                 \
            int i2  = id / (TT*8);                                                   \
            int rem = id - i2 * (TT*8);                                              \
            int t   = rem >> 3;                                                      \
            int grp = rem & 7;                                                       \
            const float* pc0 = x + (((size_t)n * CI + 2*i2) * TDIM + ((TBASE) + t)) * VDIM + 4*grp; \
            const float* pc1 = pc0 + TDIM * VDIM;                                    \
            f32x4 a0 = {0.f, 0.f, 0.f, 0.f};                                         \
            f32x4 a1 = {0.f, 0.f, 0.f, 0.f};                                         \
            if (grp < 6)      { a0 = *(const f32x4u*)pc0; a1 = *(const f32x4u*)pc1; }\
            else if (grp == 6){ a0.x = pc0[0];            a1.x = pc1[0]; }           \
            q0[j][0]=a0.x; q0[j][1]=a0.y; q0[j][2]=a0.z; q0[j][3]=a0.w;              \
            q1[j][0]=a1.x; q1[j][1]=a1.y; q1[j][2]=a1.z; q1[j][3]=a1.w;              \
        }

    #define STAGE_WRITE(BUF)                                                         \
        _Pragma("unroll")                                                            \
        for (int j = 0; j < NTASK; ++j) {                                            \
            int id  = tid + j * 256;                                                 \
            int i2  = id / (TT*8);                                                   \
            int rem = id - i2 * (TT*8);                                              \
            int t   = rem >> 3;                                                      \
            int grp = rem & 7;                                                       \
            int rr0 = ((grp & 1) << 4) + ((grp >> 1) << 2);                          \
            int rbase = t * 32 + rr0;                                                \
            int m   = rr0 & 7;                                                       \
            _Pragma("unroll")                                                        \
            for (int p = 0; p < 4; ++p) {                                            \
                int fx = ((m + p) & 7) ^ t;                                          \
                int addr = (rbase + p) * 128 + ((4*i2) ^ (fx << 4));                 \
                *(unsigned int*)((BUF) + addr) = pack2(q0[j][p], q1[j][p]);          \
            }                                                                        \
        }

    // ---- prologue: stage chunk 0; frag loads overlap the HBM wait ----
    STAGE_LOAD(t0);

    bf16x8 WB[KK][2], AB[KK][2];
    float bv[KK];
    #pragma unroll
    for (int k = 0; k < KK; ++k) {
        WB[k][0] = *(const bf16x8*)(wbuf + (((k*4 + wid)*2 + 0)*64 + lane)*4);
        WB[k][1] = *(const bf16x8*)(wbuf + (((k*4 + wid)*2 + 1)*64 + lane)*4);
        AB[k][0] = *(const bf16x8*)(abuf + ((k*2 + 0)*64 + lane)*4);
        AB[k][1] = *(const bf16x8*)(abuf + ((k*2 + 1)*64 + lane)*4);
        bv[k]    = b[k*CO + c];
    }

    STAGE_WRITE(&smem[0][0]);
    __syncthreads();

    const size_t cs = (size_t)TDIM * VDIM;   // out stride for c+1

    #pragma unroll
    for (int ch = 0; ch < NCHUNK; ++ch) {
        const char* rbuf = &smem[ch][0];
        const int   tg0  = t0 + ch * TT;

        if (ch == 0) STAGE_LOAD(t0 + TT);    // chunk1 loads in flight under compute

        #pragma unroll
        for (int t = 0; t < TT; ++t) {
            // A-frags for this t (reused across all k); rows j&7 = l15&7, j>>5 = t
            int j0 = t*32 + l15;
            int j1 = j0 + 16;
            const char* p0 = rbuf + j0*128;
            const char* p1 = rbuf + j1*128;
            int fx = ((l15 & 7) ^ t) << 4;
            bf16x8 A00 = *(const bf16x8*)(p0 + ((2*i0)      ^ fx));
            bf16x8 A01 = *(const bf16x8*)(p0 + ((2*i0 + 64) ^ fx));
            bf16x8 A10 = *(const bf16x8*)(p1 + ((2*i0)      ^ fx));
            bf16x8 A11 = *(const bf16x8*)(p1 + ((2*i0 + 64) ^ fx));

            f32x4 accA = {0.f, 0.f, 0.f, 0.f};
            f32x4 accB = {0.f, 0.f, 0.f, 0.f};
            #pragma unroll
            for (int k = 0; k < KK; ++k) {
                f32x4 D0 = {bv[k], bv[k], bv[k], bv[k]};   // bias via C-operand
                f32x4 D1 = D0;
                D0 = __builtin_amdgcn_mfma_f32_16x16x32_bf16(A00, WB[k][0], D0, 0, 0, 0);
                D0 = __builtin_amdgcn_mfma_f32_16x16x32_bf16(A01, WB[k][1], D0, 0, 0, 0);
                D1 = __builtin_amdgcn_mfma_f32_16x16x32_bf16(A10, WB[k][0], D1, 0, 0, 0);
                D1 = __builtin_amdgcn_mfma_f32_16x16x32_bf16(A11, WB[k][1], D1, 0, 0, 0);
                // lane holds y[c][v]: D0 -> v=8g+{0..3}, D1 -> v=8g+4+{0..3}
                // == exactly the stage2 A-fragment (k-elements 8g..8g+7).
                i32x4 pav = {(int)pack2(D0.x, D0.y), (int)pack2(D0.z, D0.w),
                             (int)pack2(D1.x, D1.y), (int)pack2(D1.z, D1.w)};
                bf16x8 PA = __builtin_bit_cast(bf16x8, pav);
                accA = __builtin_amdgcn_mfma_f32_16x16x32_bf16(PA, AB[k][0], accA, 0, 0, 0);
                accB = __builtin_amdgcn_mfma_f32_16x16x32_bf16(PA, AB[k][1], accB, 0, 0, 0);
            }
            // ---- store this t: D2 col=w=l15(+16*nt), rows c = wid*16 + 4g + p ----
            size_t base = (((size_t)n * CO + (wid*16 + 4*g)) * TDIM + (tg0 + t)) * VDIM + l15;
            out[base]        = accA.x;
            out[base + cs]   = accA.y;
            out[base + 2*cs] = accA.z;
            out[base + 3*cs] = accA.w;
            if (l15 < VDIM - 16) {
                size_t base2 = base + 16;
                out[base2]        = accB.x;
                out[base2 + cs]   = accB.y;
                out[base2 + 2*cs] = accB.z;
                out[base2 + 3*cs] = accB.w;
            }
        }

        if (ch == 0) {
            STAGE_WRITE(&smem[1][0]);        // lands in the idle buffer
            __syncthreads();                 // chunk1 ready
        }
    }
    #undef STAGE_LOAD
    #undef STAGE_WRITE
}

extern "C" void kernel_launch(void* const* d_in, const int* in_sizes, int n_in,
                              void* d_out, int out_size, void* d_ws, size_t ws_size,
                              hipStream_t stream) {
    const float* x = (const float*)d_in[0];
    const float* A = (const float*)d_in[1];
    const float* W = (const float*)d_in[2];
    const float* b = (const float*)d_in[3];
    float* out = (float*)d_out;

    unsigned int* wbuf = (unsigned int*)d_ws;
    unsigned int* abuf = (unsigned int*)((char*)d_ws + WBUF_BYTES);

    const size_t out_elems = (size_t)NB * CO * TDIM * VDIM;
    sgcn_prep<<<8, 256, 0, stream>>>(A, W, wbuf, abuf, out + out_elems);

    dim3 grid(GRIDX, NB);
    sgcn_fused<<<grid, 256, 0, stream>>>(x, b, wbuf, abuf, out);
}

// Round 19
// 56.911 us; speedup vs baseline: 1.0415x; 1.0294x over previous
//
#include <hip/hip_runtime.h>
#include <hip/hip_bf16.h>

// SGCN fused: y = conv1x1(x, W)+b ; out[n,c,t,w] = sum_{k,v} y[n,k,c,t,v]*A[k,v,w]
// x:[64,64,300,25] f32, A:[3,25,25] f32, W:[64,192] f32, b:[192] f32
// d_out = [out (64*64*300*25) ; A (1875)] f32
//
// Round 19 = r17/r18 pipeline at TT=3: dbuf 24.6KB -> LDS cap 6 blocks/CU
// (real slack, unlike r18's exact-fit 4x40KB=160KB which gave only 3);
// VGPR ~88 -> 5 waves/SIMD -> ~5 resident pipelined blocks (2x r18).
// Grid 50x64=3200 (12.5/CU). r15's bare-TT=3 regression was fixed costs;
// the pipeline hides them. Staging: 768 tasks/chunk = 3/thread (id/24).
// Float4 staging, t-mixed swizzle f(row)=(row&7)^(row>>5), permuted-row xs
// so stage1 D-frag == stage2 A-frag (zero shuffle), bias via MFMA C-init.

#define TT 3
#define NCHUNK 2
#define GRIDX 50                 // 300 / (TT*NCHUNK)
#define NB 64
#define CI 64
#define TDIM 300
#define VDIM 25
#define CO 64
#define KK 3
#define NTASK 3                  // staging tasks per thread = 32*TT*8/256

#define XROWS (TT*32)            // 96 rows, [96][128B], swz ((row&7)^(row>>5))<<4
#define SMEM_BYTES (XROWS*128)   // 12288 B per buffer

#define WBUF_BYTES (KK*4*2*64*16)   // 24576: [k][wave][half][lane] 16B frags
#define ABUF_BYTES (KK*2*64*16)     //  6144: [k][nt][lane] 16B frags

typedef __attribute__((ext_vector_type(8))) short bf16x8;
typedef __attribute__((ext_vector_type(4))) float f32x4;
typedef __attribute__((ext_vector_type(4))) int i32x4;
typedef __attribute__((ext_vector_type(4), aligned(4))) float f32x4u;  // 4B-aligned vec load

__device__ __forceinline__ unsigned int pack2(float lo, float hi) {
    __hip_bfloat162 h = __float22bfloat162_rn(make_float2(lo, hi));  // v_cvt_pk_bf16_f32
    unsigned int u;
    __builtin_memcpy(&u, &h, 4);
    return u;
}
__device__ __forceinline__ unsigned short f2bf(float f) {
    __hip_bfloat16 h = __float2bfloat16(f);
    unsigned short u;
    __builtin_memcpy(&u, &h, 2);
    return u;
}

// ---- prep: bf16 B-fragments for W and A in ws; copy A to out tail ----
__global__ void sgcn_prep(const float* __restrict__ A, const float* __restrict__ W,
                          unsigned int* __restrict__ wbuf, unsigned int* __restrict__ abuf,
                          float* __restrict__ outA) {
    int id = blockIdx.x * 256 + threadIdx.x;    // grid 8*256
    if (id < KK * 4 * 2 * 64) {                 // 1536 W-fragments
        int l  = id & 63;
        int h  = (id >> 6) & 1;
        int wq = (id >> 7) & 3;
        int k  = id >> 9;
        int c  = wq * 16 + (l & 15);
        int ib = (l >> 4) * 8 + h * 32;
        unsigned int pk[4];
        #pragma unroll
        for (int j = 0; j < 4; ++j)
            pk[j] = pack2(W[(size_t)(ib + 2*j)     * (KK*CO) + k*CO + c],
                          W[(size_t)(ib + 2*j + 1) * (KK*CO) + k*CO + c]);
        *(uint4*)(wbuf + id * 4) = make_uint4(pk[0], pk[1], pk[2], pk[3]);
    }
    if (id < KK * 2 * 64) {                     // 384 A-fragments, v zero-padded to 32
        int l  = id & 63;
        int nt = (id >> 6) & 1;
        int k  = id >> 7;
        int w  = nt * 16 + (l & 15);
        int vb = (l >> 4) * 8;
        unsigned int pk[4];
        #pragma unroll
        for (int j = 0; j < 4; ++j) {
            int v0 = vb + 2*j, v1 = v0 + 1;
            unsigned short u0 = (v0 < VDIM && w < VDIM) ? f2bf(A[k*VDIM*VDIM + v0*VDIM + w]) : (unsigned short)0;
            unsigned short u1 = (v1 < VDIM && w < VDIM) ? f2bf(A[k*VDIM*VDIM + v1*VDIM + w]) : (unsigned short)0;
            pk[j] = (unsigned int)u0 | ((unsigned int)u1 << 16);
        }
        *(uint4*)(abuf + id * 4) = make_uint4(pk[0], pk[1], pk[2], pk[3]);
    }
    if (id < KK * VDIM * VDIM) outA[id] = A[id];   // tuple output 1 (exact)
}

__global__ __launch_bounds__(256, 2) void sgcn_fused(
    const float* __restrict__ x, const float* __restrict__ b,
    const unsigned int* __restrict__ wbuf, const unsigned int* __restrict__ abuf,
    float* __restrict__ out)
{
    __shared__ __align__(16) char smem[2][SMEM_BYTES];
    const int tid  = threadIdx.x;
    const int lane = tid & 63;
    const int wid  = tid >> 6;
    const int n    = blockIdx.y;
    const int t0   = blockIdx.x * (TT * NCHUNK);
    const int l15  = lane & 15;
    const int g    = lane >> 4;
    const int i0   = g * 8;              // K-chunk base within 32
    const int c    = wid * 16 + l15;

    // Staging task decode: id = tid + j*256, j=0..2 over 768 tasks.
    // id -> i2 = id/24, rem = id%24, t = rem>>3, grp = rem&7; v0 = 4*grp;
    // rows rr = 16*(grp&1) + 4*(grp>>1) + p (permuted order).
    float q0[NTASK][4], q1[NTASK][4];

    #define STAGE_LOAD(TBASE)                                                        \
        _Pragma("unroll")                                                            \
        for (int j = 0; j < NTASK; ++j) {                                            \
            int id  = tid + j * 256;                                                 \
            int i2  = id / (TT*8);                                                   \
            int rem = id - i2 * (TT*8);                                              \
            int t   = rem >> 3;                                                      \
            int grp = rem & 7;                                                       \
            const float* pc0 = x + (((size_t)n * CI + 2*i2) * TDIM + ((TBASE) + t)) * VDIM + 4*grp; \
            const float* pc1 = pc0 + TDIM * VDIM;                                    \
            f32x4 a0 = {0.f, 0.f, 0.f, 0.f};                                         \
            f32x4 a1 = {0.f, 0.f, 0.f, 0.f};                                         \
            if (grp < 6)      { a0 = *(const f32x4u*)pc0; a1 = *(const f32x4u*)pc1; }\
            else if (grp == 6){ a0.x = pc0[0];            a1.x = pc1[0]; }           \
            q0[j][0]=a0.x; q0[j][1]=a0.y; q0[j][2]=a0.z; q0[j][3]=a0.w;              \
            q1[j][0]=a1.x; q1[j][1]=a1.y; q1[j][2]=a1.z; q1[j][3]=a1.w;              \
        }

    #define STAGE_WRITE(BUF)                                                         \
        _Pragma("unroll")                                                            \
        for (int j = 0; j < NTASK; ++j) {                                            \
            int id  = tid + j * 256;                                                 \
            int i2  = id / (TT*8);                                                   \
            int rem = id - i2 * (TT*8);                                              \
            int t   = rem >> 3;                                                      \
            int grp = rem & 7;                                                       \
            int rr0 = ((grp & 1) << 4) + ((grp >> 1) << 2);                          \
            int rbase = t * 32 + rr0;                                                \
            int m   = rr0 & 7;                                                       \
            _Pragma("unroll")                                                        \
            for (int p = 0; p < 4; ++p) {                                            \
                int fx = ((m + p) & 7) ^ t;                                          \
                int addr = (rbase + p) * 128 + ((4*i2) ^ (fx << 4));                 \
                *(unsigned int*)((BUF) + addr) = pack2(q0[j][p], q1[j][p]);          \
            }                                                                        \
        }

    // ---- prologue: stage chunk 0; frag loads overlap the HBM wait ----
    STAGE_LOAD(t0);

    bf16x8 WB[KK][2], AB[KK][2];
    float bv[KK];
    #pragma unroll
    for (int k = 0; k < KK; ++k) {
        WB[k][0] = *(const bf16x8*)(wbuf + (((k*4 + wid)*2 + 0)*64 + lane)*4);
        WB[k][1] = *(const bf16x8*)(wbuf + (((k*4 + wid)*2 + 1)*64 + lane)*4);
        AB[k][0] = *(const bf16x8*)(abuf + ((k*2 + 0)*64 + lane)*4);
        AB[k][1] = *(const bf16x8*)(abuf + ((k*2 + 1)*64 + lane)*4);
        bv[k]    = b[k*CO + c];
    }

    STAGE_WRITE(&smem[0][0]);
    __syncthreads();

    const size_t cs = (size_t)TDIM * VDIM;   // out stride for c+1

    #pragma unroll
    for (int ch = 0; ch < NCHUNK; ++ch) {
        const char* rbuf = &smem[ch][0];
        const int   tg0  = t0 + ch * TT;

        if (ch == 0) STAGE_LOAD(t0 + TT);    // chunk1 loads in flight under compute

        #pragma unroll
        for (int t = 0; t < TT; ++t) {
            // A-frags for this t (reused across all k); rows j&7 = l15&7, j>>5 = t
            int j0 = t*32 + l15;
            int j1 = j0 + 16;
            const char* p0 = rbuf + j0*128;
            const char* p1 = rbuf + j1*128;
            int fx = ((l15 & 7) ^ t) << 4;
            bf16x8 A00 = *(const bf16x8*)(p0 + ((2*i0)      ^ fx));
            bf16x8 A01 = *(const bf16x8*)(p0 + ((2*i0 + 64) ^ fx));
            bf16x8 A10 = *(const bf16x8*)(p1 + ((2*i0)      ^ fx));
            bf16x8 A11 = *(const bf16x8*)(p1 + ((2*i0 + 64) ^ fx));

            f32x4 accA = {0.f, 0.f, 0.f, 0.f};
            f32x4 accB = {0.f, 0.f, 0.f, 0.f};
            #pragma unroll
            for (int k = 0; k < KK; ++k) {
                f32x4 D0 = {bv[k], bv[k], bv[k], bv[k]};   // bias via C-operand
                f32x4 D1 = D0;
                D0 = __builtin_amdgcn_mfma_f32_16x16x32_bf16(A00, WB[k][0], D0, 0, 0, 0);
                D0 = __builtin_amdgcn_mfma_f32_16x16x32_bf16(A01, WB[k][1], D0, 0, 0, 0);
                D1 = __builtin_amdgcn_mfma_f32_16x16x32_bf16(A10, WB[k][0], D1, 0, 0, 0);
                D1 = __builtin_amdgcn_mfma_f32_16x16x32_bf16(A11, WB[k][1], D1, 0, 0, 0);
                // lane holds y[c][v]: D0 -> v=8g+{0..3}, D1 -> v=8g+4+{0..3}
                // == exactly the stage2 A-fragment (k-elements 8g..8g+7).
                i32x4 pav = {(int)pack2(D0.x, D0.y), (int)pack2(D0.z, D0.w),
                             (int)pack2(D1.x, D1.y), (int)pack2(D1.z, D1.w)};
                bf16x8 PA = __builtin_bit_cast(bf16x8, pav);
                accA = __builtin_amdgcn_mfma_f32_16x16x32_bf16(PA, AB[k][0], accA, 0, 0, 0);
                accB = __builtin_amdgcn_mfma_f32_16x16x32_bf16(PA, AB[k][1], accB, 0, 0, 0);
            }
            // ---- store this t: D2 col=w=l15(+16*nt), rows c = wid*16 + 4g + p ----
            size_t base = (((size_t)n * CO + (wid*16 + 4*g)) * TDIM + (tg0 + t)) * VDIM + l15;
            out[base]        = accA.x;
            out[base + cs]   = accA.y;
            out[base + 2*cs] = accA.z;
            out[base + 3*cs] = accA.w;
            if (l15 < VDIM - 16) {
                size_t base2 = base + 16;
                out[base2]        = accB.x;
                out[base2 + cs]   = accB.y;
                out[base2 + 2*cs] = accB.z;
                out[base2 + 3*cs] = accB.w;
            }
        }

        if (ch == 0) {
            STAGE_WRITE(&smem[1][0]);        // lands in the idle buffer
            __syncthreads();                 // chunk1 ready
        }
    }
    #undef STAGE_LOAD
    #undef STAGE_WRITE
}

extern "C" void kernel_launch(void* const* d_in, const int* in_sizes, int n_in,
                              void* d_out, int out_size, void* d_ws, size_t ws_size,
                              hipStream_t stream) {
    const float* x = (const float*)d_in[0];
    const float* A = (const float*)d_in[1];
    const float* W = (const float*)d_in[2];
    const float* b = (const float*)d_in[3];
    float* out = (float*)d_out;

    unsigned int* wbuf = (unsigned int*)d_ws;
    unsigned int* abuf = (unsigned int*)((char*)d_ws + WBUF_BYTES);

    const size_t out_elems = (size_t)NB * CO * TDIM * VDIM;
    sgcn_prep<<<8, 256, 0, stream>>>(A, W, wbuf, abuf, out + out_elems);

    dim3 grid(GRIDX, NB);
    sgcn_fused<<<grid, 256, 0, stream>>>(x, b, wbuf, abuf, out);
}